// Round 15
// baseline (168.079 us; speedup 1.0000x reference)
//
#include <hip/hip_runtime.h>
#include <hip/hip_bf16.h>
#include <cstdint>

typedef __attribute__((ext_vector_type(8))) short short8v;
typedef __attribute__((ext_vector_type(4))) float f32x4;

#define B_  8
#define H_  8
#define NQ_ 1024
#define NK_ 1024
#define DM_ 512
#define DK_ 64

__device__ __forceinline__ unsigned short f2bf(float f) {
  unsigned u = __float_as_uint(f);
  u += 0x7FFF + ((u >> 16) & 1);
  return (unsigned short)(u >> 16);
}

typedef const __attribute__((address_space(1))) unsigned int* gas1_t;
typedef __attribute__((address_space(3))) unsigned int* las3_t;
__device__ __forceinline__ void gload16(const void* g, void* l) {
  __builtin_amdgcn_global_load_lds((gas1_t)g, (las3_t)l, 16, 0, 0);
}

// ---------------- prep: pack_mask (blocks 0..2047) + transpose_w4 (blocks 2048..2303) ----------
__global__ __launch_bounds__(256) void prep(
    const int* __restrict__ mask, unsigned long long* __restrict__ bits,
    const float* __restrict__ s0, const float* __restrict__ s1,
    const float* __restrict__ s2, const float* __restrict__ s3,
    unsigned short* __restrict__ d0, unsigned short* __restrict__ d1,
    unsigned short* __restrict__ d2, unsigned short* __restrict__ d3) {
  __shared__ float tile[64][65];
  int bid = blockIdx.x;
  if (bid < 2048) {
    // mask [B,NQ,NK] int32 -> bitmask u64 via ballot
    int w = (bid * 256 + threadIdx.x) >> 6;  // global wave 0..8191
    int lane = threadIdx.x & 63;
#pragma unroll
    for (int i = 0; i < 16; ++i) {
      size_t chunk = (size_t)w * 16 + i;     // u64 index, 131072 total
      int v = mask[chunk * 64 + lane];
      unsigned long long bm = __ballot(v != 0);
      if (lane == 0) bits[chunk] = bm;
    }
  } else {
    int fid = bid - 2048;                    // 256 blocks = old dim3(8,8,4)
    int z = fid >> 6, rem = fid & 63;
    int r0 = (rem >> 3) * 64, c0 = (rem & 7) * 64;
    const float* src = z == 0 ? s0 : z == 1 ? s1 : z == 2 ? s2 : s3;
    unsigned short* dst = z == 0 ? d0 : z == 1 ? d1 : z == 2 ? d2 : d3;
    int t = threadIdx.x, tx = t & 63, ty = t >> 6;
#pragma unroll
    for (int r = ty; r < 64; r += 4)
      tile[r][tx] = src[(size_t)(r0 + r) * 512 + c0 + tx];
    __syncthreads();
#pragma unroll
    for (int r = ty; r < 64; r += 4)
      dst[(size_t)(c0 + r) * 512 + r0 + tx] = f2bf(tile[tx][r]);
  }
}

// ---------------- bf16 GEMM body (round-11 structure + A-load software pipeline) ----------------
// A either bf16 (gload_lds) or f32 (reg-stage + cvt + ds_write, same linear LDS layout).
// a32 A-loads are issued one K-step AHEAD (after the second barrier, before the MFMAs),
// so their ~600-900 cyc HBM latency hides under 16 MFMAs instead of being exposed at the
// next ds_write. 2x manual unroll with name-swapped register sets (static indexing).
__device__ __forceinline__ void gemm_body(
    const unsigned short* __restrict__ A,    // bf16 A (a32=false)
    const float* __restrict__ Af,            // f32 A (a32=true)
    const unsigned short* __restrict__ Bt,
    const float* __restrict__ bias,
    void* __restrict__ outp, int mode, int bx, int by, bool a32) {
  const int K = 512;
  __shared__ unsigned short As[128 * 32];
  __shared__ unsigned short Bs[128 * 32];
  int t = threadIdx.x, wave = t >> 6, lane = t & 63;
  int wr = wave >> 1, wc = wave & 1;
  int row0 = bx * 128, col0 = by * 128;
  int srow = t >> 2, scol = (t & 3) * 8;
  const unsigned short* ga = a32 ? nullptr : A + (size_t)(row0 + srow) * K + scol;
  const float* gaf = a32 ? Af + (size_t)(row0 + srow) * K + scol : nullptr;
  const unsigned short* gb = Bt + (size_t)(col0 + srow) * K + scol;
  unsigned short* lA0 = As + wave * 512;
  unsigned short* lA1 = As + 2048 + wave * 512;
  unsigned short* lB0 = Bs + wave * 512;
  unsigned short* lB1 = Bs + 2048 + wave * 512;
  int l15 = lane & 15, lk = (lane >> 4) * 8;
  f32x4 acc[4][4] = {};

  float4 pA0, pA1, pA2, pA3, qA0, qA1, qA2, qA3;

#define LOADA(R0, R1, R2, R3, KB)                              \
  do {                                                         \
    if (a32) {                                                 \
      R0 = *(const float4*)(gaf + (KB));                       \
      R1 = *(const float4*)(gaf + (KB) + 4);                   \
      R2 = *(const float4*)(gaf + (size_t)64 * K + (KB));      \
      R3 = *(const float4*)(gaf + (size_t)64 * K + (KB) + 4);  \
    }                                                          \
  } while (0)

#define GSTEP(R0, R1, R2, R3, N0, N1, N2, N3, KB)                           \
  {                                                                         \
    __syncthreads();                                                        \
    if (a32) {                                                              \
      short8v w0, w1;                                                       \
      w0[0] = (short)f2bf(R0.x); w0[1] = (short)f2bf(R0.y);                 \
      w0[2] = (short)f2bf(R0.z); w0[3] = (short)f2bf(R0.w);                 \
      w0[4] = (short)f2bf(R1.x); w0[5] = (short)f2bf(R1.y);                 \
      w0[6] = (short)f2bf(R1.z); w0[7] = (short)f2bf(R1.w);                 \
      w1[0] = (short)f2bf(R2.x); w1[1] = (short)f2bf(R2.y);                 \
      w1[2] = (short)f2bf(R2.z); w1[3] = (short)f2bf(R2.w);                 \
      w1[4] = (short)f2bf(R3.x); w1[5] = (short)f2bf(R3.y);                 \
      w1[6] = (short)f2bf(R3.z); w1[7] = (short)f2bf(R3.w);                 \
      *(short8v*)(As + srow * 32 + scol) = w0;                              \
      *(short8v*)(As + (64 + srow) * 32 + scol) = w1;                       \
    } else {                                                                \
      gload16(ga + (KB), lA0);                                              \
      gload16(ga + (size_t)64 * K + (KB), lA1);                             \
    }                                                                       \
    gload16(gb + (KB), lB0);                                                \
    gload16(gb + (size_t)64 * K + (KB), lB1);                               \
    __syncthreads();                                                        \
    if ((KB) + 32 < K) LOADA(N0, N1, N2, N3, (KB) + 32);                    \
    short8v af[4], bf[4];                                                   \
    _Pragma("unroll")                                                       \
    for (int i = 0; i < 4; ++i)                                             \
      af[i] = *(const short8v*)(As + (wr * 64 + i * 16 + l15) * 32 + lk);   \
    _Pragma("unroll")                                                       \
    for (int j = 0; j < 4; ++j)                                             \
      bf[j] = *(const short8v*)(Bs + (wc * 64 + j * 16 + l15) * 32 + lk);   \
    _Pragma("unroll")                                                       \
    for (int i = 0; i < 4; ++i)                                             \
      _Pragma("unroll")                                                     \
      for (int j = 0; j < 4; ++j)                                           \
        acc[i][j] = __builtin_amdgcn_mfma_f32_16x16x32_bf16(af[i], bf[j], acc[i][j], 0, 0, 0); \
  }

  LOADA(pA0, pA1, pA2, pA3, 0);
  for (int kb = 0; kb < K; kb += 64) {
    GSTEP(pA0, pA1, pA2, pA3, qA0, qA1, qA2, qA3, kb);
    GSTEP(qA0, qA1, qA2, qA3, pA0, pA1, pA2, pA3, kb + 32);
  }
#undef GSTEP
#undef LOADA

  int lr = (lane >> 4) * 4;
#pragma unroll
  for (int i = 0; i < 4; ++i) {
#pragma unroll
    for (int j = 0; j < 4; ++j) {
      int col = col0 + wc * 64 + j * 16 + l15;
      float bb = bias[col];
#pragma unroll
      for (int r = 0; r < 4; ++r) {
        int m = row0 + wr * 64 + i * 16 + lr + r;
        float v = acc[i][j][r] + bb;
        if (mode == 3) {
          ((float*)outp)[(size_t)m * 512 + col] = v;
        } else {
          int b = m >> 10, n = m & 1023, h = col >> 6, d = col & 63;
          unsigned short bw = f2bf(v);
          if (mode == 2)
            ((unsigned short*)outp)[(((size_t)b * H_ + h) * DK_ + d) * NK_ + n] = bw;
          else
            ((unsigned short*)outp)[(((size_t)b * H_ + h) * NQ_ + n) * DK_ + d] = bw;
        }
      }
    }
  }
}

// XCD-chunked swizzle over the 256-block 2D grid.
__device__ __forceinline__ int2 gemm_swz() {
  int fid = blockIdx.y * 64 + blockIdx.x;
  int sw = (fid & 7) * 32 + (fid >> 3);
  int2 r; r.x = sw >> 2; r.y = sw & 3;
  return r;
}

__global__ __launch_bounds__(256) void gemm_qkv(
    const float* __restrict__ A0, const float* __restrict__ A1, const float* __restrict__ A2,
    const unsigned short* __restrict__ B0, const unsigned short* __restrict__ B1,
    const unsigned short* __restrict__ B2,
    const float* __restrict__ c0, const float* __restrict__ c1, const float* __restrict__ c2,
    unsigned short* __restrict__ o0, unsigned short* __restrict__ o1,
    unsigned short* __restrict__ o2) {
  int z = blockIdx.z;
  const float* A = z == 0 ? A0 : z == 1 ? A1 : A2;
  const unsigned short* Bt = z == 0 ? B0 : z == 1 ? B1 : B2;
  const float* bias = z == 0 ? c0 : z == 1 ? c1 : c2;
  unsigned short* o = z == 0 ? o0 : z == 1 ? o1 : o2;
  int2 s = gemm_swz();
  gemm_body(nullptr, A, Bt, bias, (void*)o, z, s.x, s.y, true);
}

__global__ __launch_bounds__(256) void gemm_out(
    const unsigned short* __restrict__ A, const unsigned short* __restrict__ Bt,
    const float* __restrict__ bias, float* __restrict__ o) {
  int2 s = gemm_swz();
  gemm_body(A, nullptr, Bt, bias, (void*)o, 3, s.x, s.y, false);
}

// ---------------- fused attention (round-11, byte-identical: T4 counted-vmcnt) -------------
__global__ __launch_bounds__(256, 4) void attn_fused(
    const unsigned short* __restrict__ qw,   // [B,H,NQ,64] bf16
    const unsigned short* __restrict__ kw,   // [B,H,NK,64] bf16
    const unsigned short* __restrict__ vtw,  // [B,H,64,NK] bf16 (V transposed)
    const unsigned long long* __restrict__ mbits,  // [B,NQ,16] u64
    float* __restrict__ unnorm,              // [B,H,NQ,NK] f32 (output 1)
    unsigned short* __restrict__ ctx) {      // [B,NQ,512] bf16
  __shared__ unsigned short Ks[2][4096];     // [64 k-rows][64 d], 16B chunks XOR-swizzled
  __shared__ unsigned short Vs[2][4096];     // [64 d-rows][64 k], same swizzle
  __shared__ unsigned short Ps[4096];        // 4 waves x [16 q-rows][64 k], same swizzle
  int bid0 = blockIdx.x;
  int bid = (bid0 & 7) * 128 + (bid0 >> 3);  // XCD-chunked swizzle
  int qb = bid & 15, h = (bid >> 4) & 7, b = bid >> 7;
  int t = threadIdx.x, wave = t >> 6, lane = t & 63;
  int l15 = lane & 15, lg = lane >> 4;
  const unsigned short* qp = qw + (((size_t)b * H_ + h) * NQ_ + qb * 64 + wave * 16) * 64;
  const unsigned short* kp = kw + ((size_t)b * H_ + h) * NK_ * 64;
  const unsigned short* vp = vtw + ((size_t)b * H_ + h) * 64 * NK_;
  int srow = t >> 3;                        // staging row 0..31
  int scs = (t & 7) ^ (srow & 7);           // pre-swizzled source chunk
  const unsigned short* kbl = kp + (size_t)srow * 64 + scs * 8;
  const unsigned short* vbl = vp + (size_t)srow * NK_ + scs * 8;
  int qrow = qb * 64 + wave * 16 + l15;
  float* up = unnorm + ((size_t)(b * H_ + h) * NQ_ + qrow) * NK_ + lg * 4;
  const unsigned long long* mb = mbits + ((size_t)b * NQ_ + qrow) * 16;
  int swz0 = ((lg) ^ (l15 & 7)) * 8;
  int swz1 = ((4 | lg) ^ (l15 & 7)) * 8;
  int pbase = wave * 1024 + l15 * 64;
  short8v aq0 = *(const short8v*)(qp + (size_t)l15 * 64 + lg * 8);
  short8v aq1 = *(const short8v*)(qp + (size_t)l15 * 64 + 32 + lg * 8);

  unsigned long long mkA = mb[0], mkB;
  float mrun = -INFINITY, lrun = 0.f;
  f32x4 oacc[4] = {};

#define STAGE(NXT, KB)                                              \
  do {                                                              \
    gload16(kbl + (size_t)(KB) * 4096,        &Ks[NXT][wave * 512]);        \
    gload16(kbl + (size_t)(KB) * 4096 + 2048, &Ks[NXT][2048 + wave * 512]); \
    gload16(vbl + (size_t)(KB) * 64,              &Vs[NXT][wave * 512]);        \
    gload16(vbl + (size_t)(KB) * 64 + 32 * NK_,   &Vs[NXT][2048 + wave * 512]); \
  } while (0)

#define TILE_SYNC()                                       \
  do {                                                    \
    asm volatile("s_waitcnt vmcnt(16)" ::: "memory");     \
    __builtin_amdgcn_s_barrier();                         \
    __builtin_amdgcn_sched_barrier(0);                    \
  } while (0)

#define ATTN_TILE(KB, CUR, NXT, MKC, MKN)                                          \
  {                                                                                \
    if ((KB) < 15) STAGE(NXT, (KB) + 1);                                           \
    __builtin_amdgcn_sched_barrier(0); /* pin STAGE as the tile's oldest VMEM */   \
    MKN = mb[((KB) + 1) & 15]; /* mask prefetch one tile ahead */                  \
    unsigned long long shm = MKC >> (lg * 4);                                      \
    unsigned mlo = (unsigned)shm, mhi = (unsigned)(shm >> 32);                     \
    f32x4 s[4] = {};                                                               \
    __builtin_amdgcn_s_setprio(1);                                                 \
    _Pragma("unroll")                                                              \
    for (int j = 0; j < 4; ++j) {                                                  \
      short8v kf0 = *(const short8v*)&Ks[CUR][(j * 16 + l15) * 64 + swz0];         \
      short8v kf1 = *(const short8v*)&Ks[CUR][(j * 16 + l15) * 64 + swz1];         \
      s[j] = __builtin_amdgcn_mfma_f32_16x16x32_bf16(kf0, aq0, s[j], 0, 0, 0);     \
      s[j] = __builtin_amdgcn_mfma_f32_16x16x32_bf16(kf1, aq1, s[j], 0, 0, 0);     \
    }                                                                              \
    __builtin_amdgcn_s_setprio(0);                                                 \
    float p_[4][4];                                                                \
    float pmax = -INFINITY;                                                        \
    _Pragma("unroll")                                                              \
    for (int j = 0; j < 4; ++j) {                                                  \
      float4 st;                                                                   \
      st.x = s[j][0] * 0.125f; st.y = s[j][1] * 0.125f;                            \
      st.z = s[j][2] * 0.125f; st.w = s[j][3] * 0.125f;                            \
      *(float4*)(up + (size_t)(KB) * 64 + j * 16) = st;                            \
      p_[j][0] = st.x; p_[j][1] = st.y; p_[j][2] = st.z; p_[j][3] = st.w;          \
      pmax = fmaxf(pmax, fmaxf(fmaxf(st.x, st.y), fmaxf(st.z, st.w)));             \
    }                                                                              \
    pmax = fmaxf(pmax, __shfl_xor(pmax, 16));                                      \
    pmax = fmaxf(pmax, __shfl_xor(pmax, 32));                                      \
    float mnew = fmaxf(mrun, pmax);                                                \
    float alpha = __expf(mrun - mnew);  /* tile 0: expf(-inf)=0 */                 \
    float psum = 0.f;                                                              \
    _Pragma("unroll")                                                              \
    for (int j = 0; j < 4; ++j) {                                                  \
      unsigned mw = (j < 2) ? mlo : mhi;                                           \
      _Pragma("unroll")                                                            \
      for (int r = 0; r < 4; ++r) {                                                \
        float pv = __expf(p_[j][r] - mnew);                                        \
        pv = ((mw >> ((j & 1) * 16 + r)) & 1) ? pv : 0.f;                          \
        psum += pv;                                                                \
        p_[j][r] = pv;                                                             \
      }                                                                            \
    }                                                                              \
    psum += __shfl_xor(psum, 16);                                                  \
    psum += __shfl_xor(psum, 32);                                                  \
    lrun = lrun * alpha + psum;                                                    \
    mrun = mnew;                                                                   \
    _Pragma("unroll")                                                              \
    for (int j = 0; j < 4; ++j) {                                                  \
      ushort4 pb;                                                                  \
      pb.x = f2bf(p_[j][0]); pb.y = f2bf(p_[j][1]);                                \
      pb.z = f2bf(p_[j][2]); pb.w = f2bf(p_[j][3]);                                \
      *(ushort4*)&Ps[pbase + (((2 * j + (lg >> 1)) ^ (l15 & 7)) * 8) + (lg & 1) * 4] = pb; \
    }                                                                              \
    short8v ap0 = *(const short8v*)&Ps[pbase + swz0];                              \
    short8v ap1 = *(const short8v*)&Ps[pbase + swz1];                              \
    float av0 = __shfl(alpha, lg * 4 + 0), av1 = __shfl(alpha, lg * 4 + 1);        \
    float av2 = __shfl(alpha, lg * 4 + 2), av3 = __shfl(alpha, lg * 4 + 3);        \
    _Pragma("unroll")                                                              \
    for (int j = 0; j < 4; ++j) {                                                  \
      oacc[j][0] *= av0; oacc[j][1] *= av1;                                        \
      oacc[j][2] *= av2; oacc[j][3] *= av3;                                        \
    }                                                                              \
    __builtin_amdgcn_s_setprio(1);                                                 \
    _Pragma("unroll")                                                              \
    for (int j = 0; j < 4; ++j) {                                                  \
      short8v vf0 = *(const short8v*)&Vs[CUR][(j * 16 + l15) * 64 + swz0];         \
      short8v vf1 = *(const short8v*)&Vs[CUR][(j * 16 + l15) * 64 + swz1];         \
      oacc[j] = __builtin_amdgcn_mfma_f32_16x16x32_bf16(ap0, vf0, oacc[j], 0, 0, 0); \
      oacc[j] = __builtin_amdgcn_mfma_f32_16x16x32_bf16(ap1, vf1, oacc[j], 0, 0, 0); \
    }                                                                              \
    __builtin_amdgcn_s_setprio(0);                                                 \
    TILE_SYNC();                                                                   \
  }

  STAGE(0, 0);
  __syncthreads();
  for (int kb2 = 0; kb2 < 16; kb2 += 2) {
    ATTN_TILE(kb2, 0, 1, mkA, mkB);
    ATTN_TILE(kb2 + 1, 1, 0, mkB, mkA);
  }
#undef ATTN_TILE
#undef TILE_SYNC
#undef STAGE

  // epilogue: inv-lsum for q-rows lg*4+r via shfl, write ctx
  float lv0 = __shfl(lrun, lg * 4 + 0), lv1 = __shfl(lrun, lg * 4 + 1);
  float lv2 = __shfl(lrun, lg * 4 + 2), lv3 = __shfl(lrun, lg * 4 + 3);
  float iv[4];
  iv[0] = lv0 > 0.f ? 1.0f / lv0 : 0.0f;
  iv[1] = lv1 > 0.f ? 1.0f / lv1 : 0.0f;
  iv[2] = lv2 > 0.f ? 1.0f / lv2 : 0.0f;
  iv[3] = lv3 > 0.f ? 1.0f / lv3 : 0.0f;
#pragma unroll
  for (int r = 0; r < 4; ++r) {
    int n = qb * 64 + wave * 16 + lg * 4 + r;
    unsigned short* cp = ctx + ((size_t)b * NQ_ + n) * 512 + h * 64;
#pragma unroll
    for (int j = 0; j < 4; ++j) cp[j * 16 + l15] = f2bf(oacc[j][r] * iv[r]);
  }
}

extern "C" void kernel_launch(void* const* d_in, const int* in_sizes, int n_in,
                              void* d_out, int out_size, void* d_ws, size_t ws_size,
                              hipStream_t stream) {
  const float* queries = (const float*)d_in[0];
  const float* keys    = (const float*)d_in[1];
  const float* values  = (const float*)d_in[2];
  const int*   amask   = (const int*)d_in[3];
  const float* Wq = (const float*)d_in[4];
  const float* bq = (const float*)d_in[5];
  const float* Wk = (const float*)d_in[6];
  const float* bk = (const float*)d_in[7];
  const float* Wv = (const float*)d_in[8];
  const float* bv = (const float*)d_in[9];
  const float* Wo = (const float*)d_in[10];
  const float* bo = (const float*)d_in[11];

  float* out_f = (float*)d_out;                    // [8,1024,512]
  float* unnorm = out_f + (size_t)B_ * NQ_ * DM_;  // [8,8,1024,1024]

  char* ws = (char*)d_ws;
  size_t off = 0;
  unsigned short* Wqt = (unsigned short*)(ws + off); off += (size_t)512 * 512 * 2;
  unsigned short* Wkt = (unsigned short*)(ws + off); off += (size_t)512 * 512 * 2;
  unsigned short* Wvt = (unsigned short*)(ws + off); off += (size_t)512 * 512 * 2;
  unsigned short* Wot = (unsigned short*)(ws + off); off += (size_t)512 * 512 * 2;
  unsigned short* qws  = (unsigned short*)(ws + off); off += (size_t)8192 * 512 * 2;
  unsigned short* kws  = (unsigned short*)(ws + off); off += (size_t)8192 * 512 * 2;
  unsigned short* vtws = (unsigned short*)(ws + off); off += (size_t)8192 * 512 * 2;
  unsigned short* ctx  = (unsigned short*)(ws + off); off += (size_t)8192 * 512 * 2;
  unsigned long long* mbits = (unsigned long long*)(ws + off); off += (size_t)131072 * 8;

  prep<<<2304, 256, 0, stream>>>(amask, mbits, Wq, Wk, Wv, Wo, Wqt, Wkt, Wvt, Wot);

  gemm_qkv<<<dim3(64, 4, 3), 256, 0, stream>>>(queries, keys, values, Wqt, Wkt, Wvt,
                                               bq, bk, bv, qws, kws, vtws);

  attn_fused<<<1024, 256, 0, stream>>>(qws, kws, vtws, mbits, unnorm, ctx);

  gemm_out<<<dim3(64, 4), 256, 0, stream>>>(ctx, Wot, bo, out_f);
}

// Round 16
// 149.079 us; speedup vs baseline: 1.1274x; 1.1274x over previous
//
#include <hip/hip_runtime.h>
#include <hip/hip_bf16.h>
#include <cstdint>

typedef __attribute__((ext_vector_type(8))) short short8v;
typedef __attribute__((ext_vector_type(4))) float f32x4;

#define B_  8
#define H_  8
#define NQ_ 1024
#define NK_ 1024
#define DM_ 512
#define DK_ 64

__device__ __forceinline__ unsigned short f2bf(float f) {
  unsigned u = __float_as_uint(f);
  u += 0x7FFF + ((u >> 16) & 1);
  return (unsigned short)(u >> 16);
}

typedef const __attribute__((address_space(1))) unsigned int* gas1_t;
typedef __attribute__((address_space(3))) unsigned int* las3_t;
__device__ __forceinline__ void gload16(const void* g, void* l) {
  __builtin_amdgcn_global_load_lds((gas1_t)g, (las3_t)l, 16, 0, 0);
}

// ---------------- prep: pack_mask (blocks 0..2047) + transpose_w4 (blocks 2048..2303) ----------
__global__ __launch_bounds__(256) void prep(
    const int* __restrict__ mask, unsigned long long* __restrict__ bits,
    const float* __restrict__ s0, const float* __restrict__ s1,
    const float* __restrict__ s2, const float* __restrict__ s3,
    unsigned short* __restrict__ d0, unsigned short* __restrict__ d1,
    unsigned short* __restrict__ d2, unsigned short* __restrict__ d3) {
  __shared__ float tile[64][65];
  int bid = blockIdx.x;
  if (bid < 2048) {
    // mask [B,NQ,NK] int32 -> bitmask u64 via ballot
    int w = (bid * 256 + threadIdx.x) >> 6;  // global wave 0..8191
    int lane = threadIdx.x & 63;
#pragma unroll
    for (int i = 0; i < 16; ++i) {
      size_t chunk = (size_t)w * 16 + i;     // u64 index, 131072 total
      int v = mask[chunk * 64 + lane];
      unsigned long long bm = __ballot(v != 0);
      if (lane == 0) bits[chunk] = bm;
    }
  } else {
    int fid = bid - 2048;                    // 256 blocks = old dim3(8,8,4)
    int z = fid >> 6, rem = fid & 63;
    int r0 = (rem >> 3) * 64, c0 = (rem & 7) * 64;
    const float* src = z == 0 ? s0 : z == 1 ? s1 : z == 2 ? s2 : s3;
    unsigned short* dst = z == 0 ? d0 : z == 1 ? d1 : z == 2 ? d2 : d3;
    int t = threadIdx.x, tx = t & 63, ty = t >> 6;
#pragma unroll
    for (int r = ty; r < 64; r += 4)
      tile[r][tx] = src[(size_t)(r0 + r) * 512 + c0 + tx];
    __syncthreads();
#pragma unroll
    for (int r = ty; r < 64; r += 4)
      dst[(size_t)(c0 + r) * 512 + r0 + tx] = f2bf(tile[tx][r]);
  }
}

// ---------------- bf16 GEMM body (round-11/14 single-buffer structure, known-good) -------------
__device__ __forceinline__ void gemm_body(
    const unsigned short* __restrict__ A,    // bf16 A (a32=false)
    const float* __restrict__ Af,            // f32 A (a32=true)
    const unsigned short* __restrict__ Bt,
    const float* __restrict__ bias,
    void* __restrict__ outp, int mode, int bx, int by, bool a32) {
  const int K = 512;
  __shared__ unsigned short As[128 * 32];
  __shared__ unsigned short Bs[128 * 32];
  int t = threadIdx.x, wave = t >> 6, lane = t & 63;
  int wr = wave >> 1, wc = wave & 1;
  int row0 = bx * 128, col0 = by * 128;
  int srow = t >> 2, scol = (t & 3) * 8;
  const unsigned short* ga = a32 ? nullptr : A + (size_t)(row0 + srow) * K + scol;
  const float* gaf = a32 ? Af + (size_t)(row0 + srow) * K + scol : nullptr;
  const unsigned short* gb = Bt + (size_t)(col0 + srow) * K + scol;
  unsigned short* lA0 = As + wave * 512;
  unsigned short* lA1 = As + 2048 + wave * 512;
  unsigned short* lB0 = Bs + wave * 512;
  unsigned short* lB1 = Bs + 2048 + wave * 512;
  int l15 = lane & 15, lk = (lane >> 4) * 8;
  f32x4 acc[4][4] = {};
  for (int kb = 0; kb < K; kb += 32) {
    float4 a0, a1, a2, a3;
    if (a32) {  // issue f32 A loads before the barrier (overlap prior compute)
      a0 = *(const float4*)(gaf + kb);
      a1 = *(const float4*)(gaf + kb + 4);
      a2 = *(const float4*)(gaf + (size_t)64 * K + kb);
      a3 = *(const float4*)(gaf + (size_t)64 * K + kb + 4);
    }
    __syncthreads();
    if (a32) {
      short8v w0, w1;
      w0[0] = (short)f2bf(a0.x); w0[1] = (short)f2bf(a0.y);
      w0[2] = (short)f2bf(a0.z); w0[3] = (short)f2bf(a0.w);
      w0[4] = (short)f2bf(a1.x); w0[5] = (short)f2bf(a1.y);
      w0[6] = (short)f2bf(a1.z); w0[7] = (short)f2bf(a1.w);
      w1[0] = (short)f2bf(a2.x); w1[1] = (short)f2bf(a2.y);
      w1[2] = (short)f2bf(a2.z); w1[3] = (short)f2bf(a2.w);
      w1[4] = (short)f2bf(a3.x); w1[5] = (short)f2bf(a3.y);
      w1[6] = (short)f2bf(a3.z); w1[7] = (short)f2bf(a3.w);
      *(short8v*)(As + srow * 32 + scol) = w0;
      *(short8v*)(As + (64 + srow) * 32 + scol) = w1;
    } else {
      gload16(ga + kb, lA0);
      gload16(ga + (size_t)64 * K + kb, lA1);
    }
    gload16(gb + kb, lB0);
    gload16(gb + (size_t)64 * K + kb, lB1);
    __syncthreads();
    short8v af[4], bf[4];
#pragma unroll
    for (int i = 0; i < 4; ++i)
      af[i] = *(const short8v*)(As + (wr * 64 + i * 16 + l15) * 32 + lk);
#pragma unroll
    for (int j = 0; j < 4; ++j)
      bf[j] = *(const short8v*)(Bs + (wc * 64 + j * 16 + l15) * 32 + lk);
#pragma unroll
    for (int i = 0; i < 4; ++i)
#pragma unroll
      for (int j = 0; j < 4; ++j)
        acc[i][j] = __builtin_amdgcn_mfma_f32_16x16x32_bf16(af[i], bf[j], acc[i][j], 0, 0, 0);
  }
  int lr = (lane >> 4) * 4;
#pragma unroll
  for (int i = 0; i < 4; ++i) {
#pragma unroll
    for (int j = 0; j < 4; ++j) {
      int col = col0 + wc * 64 + j * 16 + l15;
      float bb = bias[col];
#pragma unroll
      for (int r = 0; r < 4; ++r) {
        int m = row0 + wr * 64 + i * 16 + lr + r;
        float v = acc[i][j][r] + bb;
        if (mode == 3) {
          ((float*)outp)[(size_t)m * 512 + col] = v;
        } else {
          int b = m >> 10, n = m & 1023, h = col >> 6, d = col & 63;
          unsigned short bw = f2bf(v);
          if (mode == 2)
            ((unsigned short*)outp)[(((size_t)b * H_ + h) * DK_ + d) * NK_ + n] = bw;
          else
            ((unsigned short*)outp)[(((size_t)b * H_ + h) * NQ_ + n) * DK_ + d] = bw;
        }
      }
    }
  }
}

// XCD-chunked swizzle over the 256-block 2D grid (gemm_qkv).
__device__ __forceinline__ int2 gemm_swz() {
  int fid = blockIdx.y * 64 + blockIdx.x;
  int sw = (fid & 7) * 32 + (fid >> 3);
  int2 r; r.x = sw >> 2; r.y = sw & 3;
  return r;
}

__global__ __launch_bounds__(256) void gemm_qkv(
    const float* __restrict__ A0, const float* __restrict__ A1, const float* __restrict__ A2,
    const unsigned short* __restrict__ B0, const unsigned short* __restrict__ B1,
    const unsigned short* __restrict__ B2,
    const float* __restrict__ c0, const float* __restrict__ c1, const float* __restrict__ c2,
    unsigned short* __restrict__ o0, unsigned short* __restrict__ o1,
    unsigned short* __restrict__ o2) {
  int z = blockIdx.z;
  const float* A = z == 0 ? A0 : z == 1 ? A1 : A2;
  const unsigned short* Bt = z == 0 ? B0 : z == 1 ? B1 : B2;
  const float* bias = z == 0 ? c0 : z == 1 ? c1 : c2;
  unsigned short* o = z == 0 ? o0 : z == 1 ? o1 : o2;
  int2 s = gemm_swz();
  gemm_body(nullptr, A, Bt, bias, (void*)o, z, s.x, s.y, true);
}

// ---------------- gemm_out: 64x128 tile, 512 blocks -> 2 blocks/CU (drain overlap) -------------
// Same K-loop structure/staging widths as gemm_body; A-tile is 64 rows (1 gload16/thread).
// Wave (wr,wc) of the 2x2 computes 32x64: acc[2][4].
__global__ __launch_bounds__(256) void gemm_out(
    const unsigned short* __restrict__ A, const unsigned short* __restrict__ Bt,
    const float* __restrict__ bias, float* __restrict__ o) {
  const int K = 512;
  __shared__ unsigned short As[64 * 32];
  __shared__ unsigned short Bs[128 * 32];
  int fid = blockIdx.y * 128 + blockIdx.x;   // 512 blocks (x:128, y:4)
  int sw = (fid & 7) * 64 + (fid >> 3);      // XCD-chunked, bijective
  int bx = sw >> 2, by = sw & 3;             // bx: 0..127 (M/64), by: 0..3 (N/128)
  int t = threadIdx.x, wave = t >> 6, lane = t & 63;
  int wr = wave >> 1, wc = wave & 1;
  int row0 = bx * 64, col0 = by * 128;
  int srow = t >> 2, scol = (t & 3) * 8;     // srow 0..63
  const unsigned short* ga = A + (size_t)(row0 + srow) * K + scol;
  const unsigned short* gb = Bt + (size_t)(col0 + srow) * K + scol;
  unsigned short* lA = As + wave * 512;      // 64x32 tile: exactly 256 lanes x 16B
  unsigned short* lB0 = Bs + wave * 512;
  unsigned short* lB1 = Bs + 2048 + wave * 512;
  int l15 = lane & 15, lk = (lane >> 4) * 8;
  f32x4 acc[2][4] = {};
  for (int kb = 0; kb < K; kb += 32) {
    __syncthreads();
    gload16(ga + kb, lA);
    gload16(gb + kb, lB0);
    gload16(gb + (size_t)64 * K + kb, lB1);
    __syncthreads();
    short8v af[2], bf[4];
#pragma unroll
    for (int i = 0; i < 2; ++i)
      af[i] = *(const short8v*)(As + (wr * 32 + i * 16 + l15) * 32 + lk);
#pragma unroll
    for (int j = 0; j < 4; ++j)
      bf[j] = *(const short8v*)(Bs + (wc * 64 + j * 16 + l15) * 32 + lk);
#pragma unroll
    for (int i = 0; i < 2; ++i)
#pragma unroll
      for (int j = 0; j < 4; ++j)
        acc[i][j] = __builtin_amdgcn_mfma_f32_16x16x32_bf16(af[i], bf[j], acc[i][j], 0, 0, 0);
  }
  int lr = (lane >> 4) * 4;
#pragma unroll
  for (int i = 0; i < 2; ++i) {
#pragma unroll
    for (int j = 0; j < 4; ++j) {
      int col = col0 + wc * 64 + j * 16 + l15;
      float bb = bias[col];
#pragma unroll
      for (int r = 0; r < 4; ++r) {
        int m = row0 + wr * 32 + i * 16 + lr + r;
        o[(size_t)m * 512 + col] = acc[i][j][r] + bb;
      }
    }
  }
}

// ---------------- fused attention (round-11, byte-identical: T4 counted-vmcnt) -------------
__global__ __launch_bounds__(256, 4) void attn_fused(
    const unsigned short* __restrict__ qw,   // [B,H,NQ,64] bf16
    const unsigned short* __restrict__ kw,   // [B,H,NK,64] bf16
    const unsigned short* __restrict__ vtw,  // [B,H,64,NK] bf16 (V transposed)
    const unsigned long long* __restrict__ mbits,  // [B,NQ,16] u64
    float* __restrict__ unnorm,              // [B,H,NQ,NK] f32 (output 1)
    unsigned short* __restrict__ ctx) {      // [B,NQ,512] bf16
  __shared__ unsigned short Ks[2][4096];     // [64 k-rows][64 d], 16B chunks XOR-swizzled
  __shared__ unsigned short Vs[2][4096];     // [64 d-rows][64 k], same swizzle
  __shared__ unsigned short Ps[4096];        // 4 waves x [16 q-rows][64 k], same swizzle
  int bid0 = blockIdx.x;
  int bid = (bid0 & 7) * 128 + (bid0 >> 3);  // XCD-chunked swizzle
  int qb = bid & 15, h = (bid >> 4) & 7, b = bid >> 7;
  int t = threadIdx.x, wave = t >> 6, lane = t & 63;
  int l15 = lane & 15, lg = lane >> 4;
  const unsigned short* qp = qw + (((size_t)b * H_ + h) * NQ_ + qb * 64 + wave * 16) * 64;
  const unsigned short* kp = kw + ((size_t)b * H_ + h) * NK_ * 64;
  const unsigned short* vp = vtw + ((size_t)b * H_ + h) * 64 * NK_;
  int srow = t >> 3;                        // staging row 0..31
  int scs = (t & 7) ^ (srow & 7);           // pre-swizzled source chunk
  const unsigned short* kbl = kp + (size_t)srow * 64 + scs * 8;
  const unsigned short* vbl = vp + (size_t)srow * NK_ + scs * 8;
  int qrow = qb * 64 + wave * 16 + l15;
  float* up = unnorm + ((size_t)(b * H_ + h) * NQ_ + qrow) * NK_ + lg * 4;
  const unsigned long long* mb = mbits + ((size_t)b * NQ_ + qrow) * 16;
  int swz0 = ((lg) ^ (l15 & 7)) * 8;
  int swz1 = ((4 | lg) ^ (l15 & 7)) * 8;
  int pbase = wave * 1024 + l15 * 64;
  short8v aq0 = *(const short8v*)(qp + (size_t)l15 * 64 + lg * 8);
  short8v aq1 = *(const short8v*)(qp + (size_t)l15 * 64 + 32 + lg * 8);

  unsigned long long mkA = mb[0], mkB;
  float mrun = -INFINITY, lrun = 0.f;
  f32x4 oacc[4] = {};

#define STAGE(NXT, KB)                                              \
  do {                                                              \
    gload16(kbl + (size_t)(KB) * 4096,        &Ks[NXT][wave * 512]);        \
    gload16(kbl + (size_t)(KB) * 4096 + 2048, &Ks[NXT][2048 + wave * 512]); \
    gload16(vbl + (size_t)(KB) * 64,              &Vs[NXT][wave * 512]);        \
    gload16(vbl + (size_t)(KB) * 64 + 32 * NK_,   &Vs[NXT][2048 + wave * 512]); \
  } while (0)

#define TILE_SYNC()                                       \
  do {                                                    \
    asm volatile("s_waitcnt vmcnt(16)" ::: "memory");     \
    __builtin_amdgcn_s_barrier();                         \
    __builtin_amdgcn_sched_barrier(0);                    \
  } while (0)

#define ATTN_TILE(KB, CUR, NXT, MKC, MKN)                                          \
  {                                                                                \
    if ((KB) < 15) STAGE(NXT, (KB) + 1);                                           \
    __builtin_amdgcn_sched_barrier(0); /* pin STAGE as the tile's oldest VMEM */   \
    MKN = mb[((KB) + 1) & 15]; /* mask prefetch one tile ahead */                  \
    unsigned long long shm = MKC >> (lg * 4);                                      \
    unsigned mlo = (unsigned)shm, mhi = (unsigned)(shm >> 32);                     \
    f32x4 s[4] = {};                                                               \
    __builtin_amdgcn_s_setprio(1);                                                 \
    _Pragma("unroll")                                                              \
    for (int j = 0; j < 4; ++j) {                                                  \
      short8v kf0 = *(const short8v*)&Ks[CUR][(j * 16 + l15) * 64 + swz0];         \
      short8v kf1 = *(const short8v*)&Ks[CUR][(j * 16 + l15) * 64 + swz1];         \
      s[j] = __builtin_amdgcn_mfma_f32_16x16x32_bf16(kf0, aq0, s[j], 0, 0, 0);     \
      s[j] = __builtin_amdgcn_mfma_f32_16x16x32_bf16(kf1, aq1, s[j], 0, 0, 0);     \
    }                                                                              \
    __builtin_amdgcn_s_setprio(0);                                                 \
    float p_[4][4];                                                                \
    float pmax = -INFINITY;                                                        \
    _Pragma("unroll")                                                              \
    for (int j = 0; j < 4; ++j) {                                                  \
      float4 st;                                                                   \
      st.x = s[j][0] * 0.125f; st.y = s[j][1] * 0.125f;                            \
      st.z = s[j][2] * 0.125f; st.w = s[j][3] * 0.125f;                            \
      *(float4*)(up + (size_t)(KB) * 64 + j * 16) = st;                            \
      p_[j][0] = st.x; p_[j][1] = st.y; p_[j][2] = st.z; p_[j][3] = st.w;          \
      pmax = fmaxf(pmax, fmaxf(fmaxf(st.x, st.y), fmaxf(st.z, st.w)));             \
    }                                                                              \
    pmax = fmaxf(pmax, __shfl_xor(pmax, 16));                                      \
    pmax = fmaxf(pmax, __shfl_xor(pmax, 32));                                      \
    float mnew = fmaxf(mrun, pmax);                                                \
    float alpha = __expf(mrun - mnew);  /* tile 0: expf(-inf)=0 */                 \
    float psum = 0.f;                                                              \
    _Pragma("unroll")                                                              \
    for (int j = 0; j < 4; ++j) {                                                  \
      unsigned mw = (j < 2) ? mlo : mhi;                                           \
      _Pragma("unroll")                                                            \
      for (int r = 0; r < 4; ++r) {                                                \
        float pv = __expf(p_[j][r] - mnew);                                        \
        pv = ((mw >> ((j & 1) * 16 + r)) & 1) ? pv : 0.f;                          \
        psum += pv;                                                                \
        p_[j][r] = pv;                                                             \
      }                                                                            \
    }                                                                              \
    psum += __shfl_xor(psum, 16);                                                  \
    psum += __shfl_xor(psum, 32);                                                  \
    lrun = lrun * alpha + psum;                                                    \
    mrun = mnew;                                                                   \
    _Pragma("unroll")                                                              \
    for (int j = 0; j < 4; ++j) {                                                  \
      ushort4 pb;                                                                  \
      pb.x = f2bf(p_[j][0]); pb.y = f2bf(p_[j][1]);                                \
      pb.z = f2bf(p_[j][2]); pb.w = f2bf(p_[j][3]);                                \
      *(ushort4*)&Ps[pbase + (((2 * j + (lg >> 1)) ^ (l15 & 7)) * 8) + (lg & 1) * 4] = pb; \
    }                                                                              \
    short8v ap0 = *(const short8v*)&Ps[pbase + swz0];                              \
    short8v ap1 = *(const short8v*)&Ps[pbase + swz1];                              \
    float av0 = __shfl(alpha, lg * 4 + 0), av1 = __shfl(alpha, lg * 4 + 1);        \
    float av2 = __shfl(alpha, lg * 4 + 2), av3 = __shfl(alpha, lg * 4 + 3);        \
    _Pragma("unroll")                                                              \
    for (int j = 0; j < 4; ++j) {                                                  \
      oacc[j][0] *= av0; oacc[j][1] *= av1;                                        \
      oacc[j][2] *= av2; oacc[j][3] *= av3;                                        \
    }                                                                              \
    __builtin_amdgcn_s_setprio(1);                                                 \
    _Pragma("unroll")                                                              \
    for (int j = 0; j < 4; ++j) {                                                  \
      short8v vf0 = *(const short8v*)&Vs[CUR][(j * 16 + l15) * 64 + swz0];         \
      short8v vf1 = *(const short8v*)&Vs[CUR][(j * 16 + l15) * 64 + swz1];         \
      oacc[j] = __builtin_amdgcn_mfma_f32_16x16x32_bf16(ap0, vf0, oacc[j], 0, 0, 0); \
      oacc[j] = __builtin_amdgcn_mfma_f32_16x16x32_bf16(ap1, vf1, oacc[j], 0, 0, 0); \
    }                                                                              \
    __builtin_amdgcn_s_setprio(0);                                                 \
    TILE_SYNC();                                                                   \
  }

  STAGE(0, 0);
  __syncthreads();
  for (int kb2 = 0; kb2 < 16; kb2 += 2) {
    ATTN_TILE(kb2, 0, 1, mkA, mkB);
    ATTN_TILE(kb2 + 1, 1, 0, mkB, mkA);
  }
#undef ATTN_TILE
#undef TILE_SYNC
#undef STAGE

  // epilogue: inv-lsum for q-rows lg*4+r via shfl, write ctx
  float lv0 = __shfl(lrun, lg * 4 + 0), lv1 = __shfl(lrun, lg * 4 + 1);
  float lv2 = __shfl(lrun, lg * 4 + 2), lv3 = __shfl(lrun, lg * 4 + 3);
  float iv[4];
  iv[0] = lv0 > 0.f ? 1.0f / lv0 : 0.0f;
  iv[1] = lv1 > 0.f ? 1.0f / lv1 : 0.0f;
  iv[2] = lv2 > 0.f ? 1.0f / lv2 : 0.0f;
  iv[3] = lv3 > 0.f ? 1.0f / lv3 : 0.0f;
#pragma unroll
  for (int r = 0; r < 4; ++r) {
    int n = qb * 64 + wave * 16 + lg * 4 + r;
    unsigned short* cp = ctx + ((size_t)b * NQ_ + n) * 512 + h * 64;
#pragma unroll
    for (int j = 0; j < 4; ++j) cp[j * 16 + l15] = f2bf(oacc[j][r] * iv[r]);
  }
}

extern "C" void kernel_launch(void* const* d_in, const int* in_sizes, int n_in,
                              void* d_out, int out_size, void* d_ws, size_t ws_size,
                              hipStream_t stream) {
  const float* queries = (const float*)d_in[0];
  const float* keys    = (const float*)d_in[1];
  const float* values  = (const float*)d_in[2];
  const int*   amask   = (const int*)d_in[3];
  const float* Wq = (const float*)d_in[4];
  const float* bq = (const float*)d_in[5];
  const float* Wk = (const float*)d_in[6];
  const float* bk = (const float*)d_in[7];
  const float* Wv = (const float*)d_in[8];
  const float* bv = (const float*)d_in[9];
  const float* Wo = (const float*)d_in[10];
  const float* bo = (const float*)d_in[11];

  float* out_f = (float*)d_out;                    // [8,1024,512]
  float* unnorm = out_f + (size_t)B_ * NQ_ * DM_;  // [8,8,1024,1024]

  char* ws = (char*)d_ws;
  size_t off = 0;
  unsigned short* Wqt = (unsigned short*)(ws + off); off += (size_t)512 * 512 * 2;
  unsigned short* Wkt = (unsigned short*)(ws + off); off += (size_t)512 * 512 * 2;
  unsigned short* Wvt = (unsigned short*)(ws + off); off += (size_t)512 * 512 * 2;
  unsigned short* Wot = (unsigned short*)(ws + off); off += (size_t)512 * 512 * 2;
  unsigned short* qws  = (unsigned short*)(ws + off); off += (size_t)8192 * 512 * 2;
  unsigned short* kws  = (unsigned short*)(ws + off); off += (size_t)8192 * 512 * 2;
  unsigned short* vtws = (unsigned short*)(ws + off); off += (size_t)8192 * 512 * 2;
  unsigned short* ctx  = (unsigned short*)(ws + off); off += (size_t)8192 * 512 * 2;
  unsigned long long* mbits = (unsigned long long*)(ws + off); off += (size_t)131072 * 8;

  prep<<<2304, 256, 0, stream>>>(amask, mbits, Wq, Wk, Wv, Wo, Wqt, Wkt, Wvt, Wot);

  gemm_qkv<<<dim3(64, 4, 3), 256, 0, stream>>>(queries, keys, values, Wqt, Wkt, Wvt,
                                               bq, bk, bv, qws, kws, vtws);

  attn_fused<<<1024, 256, 0, stream>>>(qws, kws, vtws, mbits, unnorm, ctx);

  gemm_out<<<dim3(128, 4), 256, 0, stream>>>(ctx, Wot, bo, out_f);
}